// Round 4
// baseline (317.985 us; speedup 1.0000x reference)
//
#include <hip/hip_runtime.h>

// Problem constants: T=2048, B=8, IN=1024, OUT=1024, N_MODULES=16, K=2
#define T_DIM   2048
#define B_DIM   8
#define IN_DIM  1024
#define OUT_DIM 1024
#define NMOD    16
#define KSLOT   2

typedef __bf16 bf16x8 __attribute__((ext_vector_type(8)));
typedef float  f32x4  __attribute__((ext_vector_type(4)));
typedef unsigned short ushort8 __attribute__((ext_vector_type(8)));

// fp32 -> bf16 round-to-nearest-even (inputs have no NaNs)
__device__ __forceinline__ unsigned short f2bf_rne(float f) {
  unsigned int u = __float_as_uint(f);
  u += 0x7fffu + ((u >> 16) & 1u);
  return (unsigned short)(u >> 16);
}

// Convert fp32 -> bf16 AND pre-pack into MFMA A/B fragment order.
// xf element index: (((b*128 + g)*128 + KG)*16 + LM)*8 + j  holds x[t=16g+LM][b][k=8KG+j]
// wf element index: (((e*64  + g)*128 + KG)*16 + LM)*8 + j  holds w[e][o=16g+LM][k=8KG+j]
// => a wave's fragment load for k-step is base + lane*16B: one coalesced 1KiB dwordx4.
__global__ __launch_bounds__(256) void convert_pack(
    const float* __restrict__ x, const float* __restrict__ w,
    unsigned short* __restrict__ xf, unsigned short* __restrict__ wf) {
  const int tid = blockIdx.x * blockDim.x + threadIdx.x;       // < 2^22
  const int XV = 1 << 21;                                      // x vectors of 8
  const float* src;
  unsigned short* dst;
  if (tid < XV) {
    const int v = tid;
    const int lm = v & 15, kg = (v >> 4) & 127, g = (v >> 11) & 127, b = v >> 18;
    src = x + (long)(16 * g + lm) * (B_DIM * IN_DIM) + b * IN_DIM + 8 * kg;
    dst = xf + (long)v * 8;
  } else {
    const int v = tid - XV;
    const int lm = v & 15, kg = (v >> 4) & 127, g = (v >> 11) & 63, e = v >> 17;
    src = w + (long)e * (OUT_DIM * IN_DIM) + (long)(16 * g + lm) * IN_DIM + 8 * kg;
    dst = wf + (long)v * 8;
  }
  float4 a = ((const float4*)src)[0];
  float4 c = ((const float4*)src)[1];
  ushort8 o;
  o[0] = f2bf_rne(a.x); o[1] = f2bf_rne(a.y); o[2] = f2bf_rne(a.z); o[3] = f2bf_rne(a.w);
  o[4] = f2bf_rne(c.x); o[5] = f2bf_rne(c.y); o[6] = f2bf_rne(c.z); o[7] = f2bf_rne(c.w);
  *(ushort8*)dst = o;
}

// Barrier-free, LDS-free GEMM: fragments load straight from the pre-packed arrays
// into VGPRs (reuse served by L1/L2/LLC; xf+wf = 64 MiB, fully LLC-resident).
// Block = 128x128 tile, 4 waves of 64x64, K-loop = 32 steps of K=32.
__global__ __launch_bounds__(256, 3) void gemm_frag(
    const unsigned short* __restrict__ xf, const unsigned short* __restrict__ wf,
    const int* __restrict__ sel, float* __restrict__ out) {
  const int nt = blockIdx.x;           // OUT tile: 0..7
  const int mt = blockIdx.y;           // T tile:   0..15
  const int bk = blockIdx.z;           // 0..15 -> (b, k)
  const int b  = bk >> 1;
  const int ks_slot = bk & 1;
  const int e  = sel[bk];

  const int tid  = threadIdx.x;
  const int lane = tid & 63;
  const int wave = tid >> 6;
  const int wm = (wave >> 1) * 64;
  const int wn = (wave & 1) * 64;

  // Fragment-group base pointers; group stride = 128*128 = 16384 elems (32 KiB)
  const unsigned short* ap[4];
  const unsigned short* bp[4];
  #pragma unroll
  for (int i = 0; i < 4; ++i) {
    const int ga = b * 128 + mt * 8 + (wm >> 4) + i;
    ap[i] = xf + (long)ga * 16384 + lane * 8;
    const int gb = e * 64 + nt * 8 + (wn >> 4) + i;
    bp[i] = wf + (long)gb * 16384 + lane * 8;
  }

  f32x4 acc[4][4];
  const f32x4 z = {0.f, 0.f, 0.f, 0.f};
  #pragma unroll
  for (int i = 0; i < 4; ++i)
    #pragma unroll
    for (int j = 0; j < 4; ++j) acc[i][j] = z;

  // Pure load->MFMA loop; no barriers/LDS, so the scheduler can hoist next-step
  // loads over current-step MFMAs with fine-grained vmcnt (AITER-style overlap).
  #pragma unroll 2
  for (int ks = 0; ks < 32; ++ks) {
    bf16x8 af[4], bfr[4];
    #pragma unroll
    for (int i = 0; i < 4; ++i) {
      af[i]  = *(const bf16x8*)(ap[i] + ks * 512);
      bfr[i] = *(const bf16x8*)(bp[i] + ks * 512);
    }
    #pragma unroll
    for (int mi = 0; mi < 4; ++mi)
      #pragma unroll
      for (int ni = 0; ni < 4; ++ni)
        acc[mi][ni] = __builtin_amdgcn_mfma_f32_16x16x32_bf16(af[mi], bfr[ni], acc[mi][ni], 0, 0, 0);
  }

  // Epilogue. C/D layout (m89-verified): col = lane&15, row = (lane>>4)*4 + reg
  const int lm = lane & 15;
  const int kg = lane >> 4;
  const int row0 = mt * 128 + wm + kg * 4;
  const int col0 = nt * 128 + wn + lm;
  #pragma unroll
  for (int mi = 0; mi < 4; ++mi) {
    #pragma unroll
    for (int r = 0; r < 4; ++r) {
      const int t = row0 + mi * 16 + r;
      float* po = out + (long)t * (B_DIM * KSLOT * OUT_DIM)
                      + b * (KSLOT * OUT_DIM) + ks_slot * OUT_DIM + col0;
      #pragma unroll
      for (int ni = 0; ni < 4; ++ni)
        po[ni * 16] = acc[mi][ni][r];
    }
  }
}

extern "C" void kernel_launch(void* const* d_in, const int* in_sizes, int n_in,
                              void* d_out, int out_size, void* d_ws, size_t ws_size,
                              hipStream_t stream) {
  const float* x   = (const float*)d_in[0];   // [T][B][IN] fp32
  const int*   sel = (const int*)d_in[1];     // [B][K] int32
  const float* w   = (const float*)d_in[2];   // [NMOD][OUT][IN] fp32
  float* out = (float*)d_out;                 // [T][B][K*OUT] fp32

  unsigned short* xf = (unsigned short*)d_ws;                 // 32 MiB bf16 fragment-packed x
  unsigned short* wf = xf + (long)T_DIM * B_DIM * IN_DIM;     // 32 MiB bf16 fragment-packed w

  const int total_vecs = (1 << 22);                           // (16M + 16M) elems / 8
  convert_pack<<<dim3(total_vecs / 256), 256, 0, stream>>>(x, w, xf, wf);

  dim3 ggrid(OUT_DIM / 128, T_DIM / 128, B_DIM * KSLOT);
  gemm_frag<<<ggrid, 256, 0, stream>>>(xf, wf, sel, out);
}

// Round 5
// 292.042 us; speedup vs baseline: 1.0888x; 1.0888x over previous
//
#include <hip/hip_runtime.h>

// Problem constants: T=2048, B=8, IN=1024, OUT=1024, N_MODULES=16, K=2
#define T_DIM   2048
#define B_DIM   8
#define IN_DIM  1024
#define OUT_DIM 1024
#define NMOD    16
#define KSLOT   2

// GEMM tiling: 128(M=T) x 256(N=OUT) block tile, BK=64, 4 waves of 64x128
#define BM 128
#define BN 256
#define BK 64

typedef __bf16 bf16x8 __attribute__((ext_vector_type(8)));
typedef float  f32x4  __attribute__((ext_vector_type(4)));
typedef unsigned short ushort8 __attribute__((ext_vector_type(8)));

typedef const __attribute__((address_space(1))) void* gptr_t;
typedef __attribute__((address_space(3))) void* lptr_t;

__device__ __forceinline__ void async_load16(const void* gp, void* lp) {
  __builtin_amdgcn_global_load_lds((gptr_t)gp, (lptr_t)lp, 16, 0, 0);
}

// fp32 -> bf16 round-to-nearest-even (inputs have no NaNs)
__device__ __forceinline__ unsigned short f2bf_rne(float f) {
  unsigned int u = __float_as_uint(f);
  u += 0x7fffu + ((u >> 16) & 1u);
  return (unsigned short)(u >> 16);
}

// Streaming prepass: x [T][B][IN] fp32 -> xb same layout bf16; w -> wb bf16.
__global__ __launch_bounds__(256) void convert_bf16(
    const float* __restrict__ x, const float* __restrict__ w,
    unsigned short* __restrict__ xb, unsigned short* __restrict__ wb) {
  const long tid = (long)blockIdx.x * blockDim.x + threadIdx.x;
  const long XV = (long)T_DIM * B_DIM * IN_DIM / 8;
  const float4* src;
  unsigned short* dst;
  long v;
  if (tid < XV) { v = tid;      src = (const float4*)x; dst = xb; }
  else          { v = tid - XV; src = (const float4*)w; dst = wb; }
  float4 a = src[2 * v];
  float4 c = src[2 * v + 1];
  ushort8 o;
  o[0] = f2bf_rne(a.x); o[1] = f2bf_rne(a.y); o[2] = f2bf_rne(a.z); o[3] = f2bf_rne(a.w);
  o[4] = f2bf_rne(c.x); o[5] = f2bf_rne(c.y); o[6] = f2bf_rne(c.z); o[7] = f2bf_rne(c.w);
  *(ushort8*)(dst + v * 8) = o;
}

// One GEMM per blockIdx.z slot (b,k): C[t,o] = sum_i xb[t][b][i] * wb[sel[b,k]][o][i]
// LDS row-major [rows][BK] staged as 16-B chunks with source-side XOR swizzle
// (slot c holds source row=c>>3, colgrp=(c&7)^(row&7)) -> ds_read_b128 conflict-free
// (verified 0 in R3) while global_load_lds writes stay lane-contiguous.
__global__ __launch_bounds__(256, 2) void gemm_mod(
    const unsigned short* __restrict__ xb, const unsigned short* __restrict__ wb,
    const int* __restrict__ sel, float* __restrict__ out) {
  __shared__ alignas(16) unsigned short As[BM * BK];   // 16 KiB
  __shared__ alignas(16) unsigned short Bs[BN * BK];   // 32 KiB

  const int nt = blockIdx.x;           // OUT tile: 0..3
  const int mt = blockIdx.y;           // T tile:   0..15
  const int bk = blockIdx.z;           // 0..15 -> (b, k)
  const int b  = bk >> 1;
  const int ks_slot = bk & 1;
  const int expert = sel[bk];

  const int AS_STRIDE = B_DIM * IN_DIM;  // 8192
  const unsigned short* A  = xb + ((long)mt * BM * B_DIM + b) * IN_DIM;
  const unsigned short* Bw = wb + ((long)expert * OUT_DIM + (long)nt * BN) * IN_DIM;

  const int tid  = threadIdx.x;
  const int lane = tid & 63;

  // A: 1024 chunks -> 4/thread.  B: 2048 chunks -> 8/thread.
  long aoff[4];
  int  alds[4];
  #pragma unroll
  for (int j = 0; j < 4; ++j) {
    const int c = tid + j * 256;
    const int r = c >> 3;
    const int g = (c & 7) ^ (r & 7);
    aoff[j] = (long)r * AS_STRIDE + g * 8;
    alds[j] = c * 8;
  }
  long boff[8];
  int  blds[8];
  #pragma unroll
  for (int j = 0; j < 8; ++j) {
    const int c = tid + j * 256;
    const int r = c >> 3;
    const int g = (c & 7) ^ (r & 7);
    boff[j] = (long)r * IN_DIM + g * 8;
    blds[j] = c * 8;
  }

  const int lm = lane & 15;            // MFMA m/n index
  const int kg = lane >> 4;            // MFMA k-group (0..3)
  const int rsw = lm & 7;              // row-derived swizzle term (rows offset by mult of 8)

  const int wave = tid >> 6;           // 4 waves: 2(M) x 2(N); wave tile 64 x 128
  const int wm = (wave >> 1) * 64;
  const int wn = (wave & 1) * 128;

  f32x4 acc[4][8];
  const f32x4 z = {0.f, 0.f, 0.f, 0.f};
  #pragma unroll
  for (int i = 0; i < 4; ++i)
    #pragma unroll
    for (int j = 0; j < 8; ++j) acc[i][j] = z;

  for (int kt = 0; kt < IN_DIM; kt += BK) {
    __syncthreads();                   // previous iter's ds_reads done before overwrite
    #pragma unroll
    for (int j = 0; j < 4; ++j)
      async_load16(A + aoff[j] + kt, &As[alds[j]]);
    #pragma unroll
    for (int j = 0; j < 8; ++j)
      async_load16(Bw + boff[j] + kt, &Bs[blds[j]]);
    __syncthreads();                   // drains vmcnt(0) before s_barrier

    #pragma unroll
    for (int kst = 0; kst < 2; ++kst) {  // two K=32 steps inside BK=64
      const int gsel = (kst * 4 + kg);
      bf16x8 af[4], bfr[8];
      #pragma unroll
      for (int mi = 0; mi < 4; ++mi) {
        const int row = wm + mi * 16 + lm;
        af[mi] = *(const bf16x8*)&As[(row * 8 + (gsel ^ rsw)) * 8];
      }
      #pragma unroll
      for (int ni = 0; ni < 8; ++ni) {
        const int row = wn + ni * 16 + lm;
        bfr[ni] = *(const bf16x8*)&Bs[(row * 8 + (gsel ^ rsw)) * 8];
      }
      #pragma unroll
      for (int mi = 0; mi < 4; ++mi)
        #pragma unroll
        for (int ni = 0; ni < 8; ++ni)
          acc[mi][ni] = __builtin_amdgcn_mfma_f32_16x16x32_bf16(af[mi], bfr[ni], acc[mi][ni], 0, 0, 0);
    }
  }

  // Epilogue. C/D layout (m89-verified): col = lane&15, row = (lane>>4)*4 + reg
  const int row0 = mt * BM + wm + kg * 4;
  const int col0 = nt * BN + wn + lm;
  #pragma unroll
  for (int mi = 0; mi < 4; ++mi) {
    #pragma unroll
    for (int r = 0; r < 4; ++r) {
      const int t = row0 + mi * 16 + r;
      float* po = out + (long)t * (B_DIM * KSLOT * OUT_DIM)
                      + b * (KSLOT * OUT_DIM) + ks_slot * OUT_DIM + col0;
      #pragma unroll
      for (int ni = 0; ni < 8; ++ni)
        po[ni * 16] = acc[mi][ni][r];
    }
  }
}

extern "C" void kernel_launch(void* const* d_in, const int* in_sizes, int n_in,
                              void* d_out, int out_size, void* d_ws, size_t ws_size,
                              hipStream_t stream) {
  const float* x   = (const float*)d_in[0];   // [T][B][IN] fp32
  const int*   sel = (const int*)d_in[1];     // [B][K] int32
  const float* w   = (const float*)d_in[2];   // [NMOD][OUT][IN] fp32
  float* out = (float*)d_out;                 // [T][B][K*OUT] fp32

  unsigned short* xb = (unsigned short*)d_ws;                 // 32 MiB bf16 [T][B][IN]
  unsigned short* wb = xb + (long)T_DIM * B_DIM * IN_DIM;     // 32 MiB bf16 [NMOD][OUT][IN]

  const long total_vecs =
      ((long)T_DIM * B_DIM * IN_DIM + (long)NMOD * OUT_DIM * IN_DIM) / 8;
  convert_bf16<<<dim3((unsigned)((total_vecs + 255) / 256)), 256, 0, stream>>>(x, w, xb, wb);

  dim3 ggrid(OUT_DIM / BN, T_DIM / BM, B_DIM * KSLOT);
  gemm_mod<<<ggrid, 256, 0, stream>>>(xb, wb, sel, out);
}